// Round 20
// baseline (95.957 us; speedup 1.0000x reference)
//
#include <hip/hip_runtime.h>
#include <math.h>

// ---------------------------------------------------------------------------
// MutilLocalLoss on MI355X.
// Level constants (match Python int()/round() semantics exactly):
//   lev: C,  A,  CROP, TOP, OH, TJW, TJN, NTILES, CSPLIT, RSPLIT, CHUNKS, START
//   0:   64, 16,  6,    5,  11,  8,   2,    6,     8,      1,      1,      0
//   1:   32, 32, 13,   10,  20,  8,   3,   15,    16,      1,      1,    968
//   2:   16, 64, 26,   19,  39,  8,   5,   50,     8,      4,      1,   4168
//   3:    8,128, 53,   38,  76,  4,  19,  361,     8,      8,      6,  16336
// R3-R19 history: VALUBusy pinned 33-37% across ALL structural changes.
// R19 killed the TA theory (coalesced LDS staging: no change, +bank conflicts).
// Surviving arithmetic: L3 tail = 384 blocks on 256 CUs (1.5/CU, 2:1
// imbalance) x ~20% per-wave duty = 33%. R13's RSPLIT fix lost to halo FMA.
// R20: halo-FREE parallelism: L3 tile 4x8 -> 4x4. 76=19x4 exactly -> no
// clamp/overlap/waste; NTILES 361, CHUNKS 6 -> 768 L3 blocks = 3/CU even.
// SLAB reverted (R19 loss). L0/1/2 unchanged (TJW=8).
// ws floats: [0,32) sc(fallback); [32,1056) prep parts; [1056,1056+245)
//            loss block sums (partial path) / corr final (fallback);
//            [63600,915008) per-pack corr partials (3.7MB; fallback else).
// ---------------------------------------------------------------------------

#define WS_SC 0
#define WS_PART 32
#define WS_CORR 1056
#define N_ENTRIES 62544
#define PB0 63600
#define PB1 65536
#define PB2 78336
#define PB3 175680
#define WS_NEED_BYTES 3700000

__device__ __forceinline__ float block_sum256(float v, float* sw) {
#pragma unroll
  for (int o = 32; o > 0; o >>= 1) v += __shfl_down(v, o, 64);
  if ((threadIdx.x & 63) == 0) sw[threadIdx.x >> 6] = v;
  __syncthreads();
  float r = (threadIdx.x < 4) ? sw[threadIdx.x] : 0.0f;
  r += __shfl_down(r, 2, 64);
  r += __shfl_down(r, 1, 64);
  __syncthreads();
  return r;  // total valid in thread 0
}

// ---------------- init: zero corr accumulators + out (FALLBACK only) --------
__global__ __launch_bounds__(256) void init_kernel(float* __restrict__ ws,
                                                   float* __restrict__ out) {
  const int e = blockIdx.x * 256 + threadIdx.x;
  if (e < N_ENTRIES) ws[WS_CORR + e] = 0.0f;
  if (e == 0) out[0] = 0.0f;
}

// ---------------- prep stage 1: 16-way sliced partial energies --------------
template <int C, int A, int CROP, int TOP>
__device__ void prep_partial_level(const float* __restrict__ grd,
                                   const float* __restrict__ sat,
                                   const float* __restrict__ mask, int b, int k,
                                   float* __restrict__ part, float* sw) {
  const float* gb = grd + (size_t)b * C * A * A;
  float s1 = 0.0f;
  constexpr int N1 = C * CROP * CROP;
  for (int idx = k * 256 + (int)threadIdx.x; idx < N1; idx += 4096) {
    int c = idx / (CROP * CROP);
    int r = idx - c * (CROP * CROP);
    int h = r / CROP;
    int w = r - h * CROP;
    float m = mask[(TOP + h) * A + (TOP + w)];
    float g = gb[((size_t)c * A + (TOP + h)) * A + (TOP + w)] * m;
    s1 += g * g;
  }
  s1 = block_sum256(s1, sw);
  const float4* sb = (const float4*)(sat + (size_t)b * C * A * A);
  const float4* m4 = (const float4*)mask;
  float s2 = 0.0f;
  constexpr int NV = C * A * A / 4;
  constexpr int MV = A * A / 4;
  for (int v = k * 256 + (int)threadIdx.x; v < NV; v += 4096) {
    float4 sv = sb[v];
    float4 mv = m4[v & (MV - 1)];
    s2 += sv.x * sv.x * mv.x + sv.y * sv.y * mv.y + sv.z * sv.z * mv.z +
          sv.w * sv.w * mv.w;
  }
  s2 = block_sum256(s2, sw);
  if (threadIdx.x == 0) {
    part[0] = s1;
    part[1] = s2;
  }
}

__global__ __launch_bounds__(256) void prep_partial_kernel(
    const float* g0, const float* s0, const float* m0, const float* g1,
    const float* s1, const float* m1, const float* g2, const float* s2,
    const float* m2, const float* g3, const float* s3, const float* m3,
    float* ws) {
  __shared__ float sw[4];
  const int pair = blockIdx.x >> 4;   // 0..31
  const int k = blockIdx.x & 15;      // slice 0..15
  const int lev = pair >> 3;
  const int b = pair & 7;
  float* part = ws + WS_PART + (pair * 16 + k) * 2;
  if (lev == 0)      prep_partial_level<64, 16, 6, 5>(g0, s0, m0, b, k, part, sw);
  else if (lev == 1) prep_partial_level<32, 32, 13, 10>(g1, s1, m1, b, k, part, sw);
  else if (lev == 2) prep_partial_level<16, 64, 26, 19>(g2, s2, m2, b, k, part, sw);
  else               prep_partial_level<8, 128, 53, 38>(g3, s3, m3, b, k, part, sw);
}

// ---------------- prep stage 2 (FALLBACK only) ------------------------------
__global__ __launch_bounds__(64) void prep_final_kernel(float* __restrict__ ws) {
  const int t = threadIdx.x;
  if (t < 32) {
    float s1 = 0.0f, s2 = 0.0f;
    const float* p = ws + WS_PART + t * 32;
    for (int k = 0; k < 16; ++k) {
      s1 += p[2 * k];
      s2 += p[2 * k + 1];
    }
    float norm = sqrtf(s1);
    float denom = fmaxf(sqrtf(s2 + 1e-8f), 1e-6f);
    ws[WS_SC + t] = 2.0f / (fmaxf(norm, 1e-12f) * denom);
  }
}

// ---------------- corr: 4xTJW-tile partials, b128 filter reads --------------
template <bool PARTIAL, int PBASE, int C, int A, int CROP, int TOP, int OH,
          int TJW, int TJN, int NTILES, int CSPLIT, int RSPLIT, int CHUNKS,
          int START>
__device__ void corr_level(int rel, int wv, int lane,
                           const float* __restrict__ grd,
                           const float* __restrict__ sat,
                           const float* __restrict__ mask,
                           float* __restrict__ ws, float* g_lds,
                           float* r_lds) {
  constexpr int CSP = C / CSPLIT;
  constexpr int OW = OH;
  constexpr int RS4 = (CROP + 3) & ~3;            // padded filter row (floats)
  constexpr int NV = (CROP + TJW - 1 + 3) / 4;    // quads covering the span
  constexpr int TAIL = CROP + TJW - 1 - 4 * (NV - 1);  // 1..4 tail elements
  constexpr int NPACK = CSPLIT * RSPLIT / 4;
  constexpr int E = 8 * OH * OW;
  constexpr int NACC = 4 * TJW;                   // accs per lane (16 or 32)
  // rel -> (b, chunk, pack); wave wv covers slice pack*4+wv
  const int b = rel / (CHUNKS * NPACK);
  int r2 = rel - b * (CHUNKS * NPACK);
  const int chunk = r2 / NPACK;
  const int pack = r2 - chunk * NPACK;
  const int sl = pack * 4 + wv;
  const int cs = sl / RSPLIT;
  const int rs = sl - cs * RSPLIT;
  const int c0 = cs * CSP;
  const int r0 = (rs * CROP) / RSPLIT;            // filter-row slice [r0, r1)
  const int r1 = ((rs + 1) * CROP) / RSPLIT;
  const int nr = r1 - r0;

  // stage masked filter slice, rows padded to RS4, pad zeroed (<=416 floats)
  const float* gb = grd + (size_t)(b * C + c0) * A * A;
  for (int c = 0; c < CSP; ++c)
    for (int h = 0; h < nr; ++h)
      if (lane < RS4)
        g_lds[(c * nr + h) * RS4 + lane] =
            (lane < CROP)
                ? gb[((size_t)c * A + (TOP + r0 + h)) * A + (TOP + lane)] *
                      mask[(TOP + r0 + h) * A + (TOP + lane)]
                : 0.0f;
  __syncthreads();

  const int s = chunk * 64 + lane;
  const bool active = s < NTILES;
  const int ss = active ? s : chunk * 64;
  const int ii = ss / TJN;
  const int jj = ss - ii * TJN;
  const int i0 = min(ii * 4, OH - 4);     // clamp; ownership masks below
  const int j0 = min(jj * TJW, OW - TJW); // L3/TJW=4: never clamps (76=19*4)
  const int own_i = ii * 4 - i0;
  const int own_j = jj * TJW - j0;
  const int amax = A - 1 - j0;            // last valid srow index

  float acc[4][TJW] = {};
  const float* sb =
      sat + (size_t)(b * C + c0) * A * A + (size_t)(i0 + r0) * A + j0;
#pragma unroll 1
  for (int c = 0; c < CSP; ++c) {
    const float* satc = sb + (size_t)c * A * A;
    const float* gl = g_lds + c * nr * RS4;
#pragma unroll 1
    for (int r = 0; r < nr + 3; ++r) {
      // load sat row window once; feeds up to 4 output rows x TJW cols
      float rbuf[NV * 4];
      const float* srow = satc + (size_t)r * A;
#pragma unroll
      for (int k = 0; k < NV - 1; ++k) {  // provably in-bounds for all tiles
        float4 t = *(const float4*)(srow + 4 * k);
        rbuf[4 * k + 0] = t.x;
        rbuf[4 * k + 1] = t.y;
        rbuf[4 * k + 2] = t.z;
        rbuf[4 * k + 3] = t.w;
      }
#pragma unroll
      for (int q = 0; q < TAIL; ++q) {   // predicated tail, true positions
        const int idx = 4 * (NV - 1) + q;
        rbuf[idx] = (idx <= amax) ? srow[idx] : 0.0f;
      }
#pragma unroll
      for (int ti = 0; ti < 4; ++ti) {
        const int h = r - ti;  // filter row for output row i0+ti
        if ((unsigned)h < (unsigned)nr) {  // wave-uniform guard
          const float* grow = gl + h * RS4;
#pragma unroll
          for (int w4 = 0; w4 < RS4 / 4; ++w4) {
            const float4 gq = *(const float4*)(grow + 4 * w4);  // ds_read_b128
#pragma unroll
            for (int gi = 0; gi < 4; ++gi) {
              const int w = 4 * w4 + gi;
              if (w < CROP) {  // compile-time: pad lanes dropped
                const float g = (gi == 0) ? gq.x : (gi == 1) ? gq.y
                                : (gi == 2) ? gq.z : gq.w;
#pragma unroll
                for (int tj = 0; tj < TJW; ++tj)
                  acc[ti][tj] = fmaf(rbuf[w + tj], g, acc[ti][tj]);
              }
            }
          }
        }
      }
    }
  }

  // --- block reduction: 4 waves hold partials for the SAME tile map -------
  // NACC accs merged in NACC/16 passes through r_lds[16][4][64] (16KB).
#pragma unroll
  for (int p = 0; p < NACC / 16; ++p) {
    if (p) __syncthreads();
#pragma unroll
    for (int k2 = 0; k2 < 16; ++k2) {
      const int gk = p * 16 + k2;
      r_lds[(k2 * 4 + wv) * 64 + lane] = acc[gk / TJW][gk % TJW];
    }
    __syncthreads();
#pragma unroll
    for (int kk = 0; kk < 4; ++kk) {
      const int k2 = wv * 4 + kk;
      const int gk = p * 16 + k2;
      const int ti = gk / TJW;
      const int tj = gk % TJW;
      const float v = r_lds[(k2 * 4 + 0) * 64 + lane] +
                      r_lds[(k2 * 4 + 1) * 64 + lane] +
                      r_lds[(k2 * 4 + 2) * 64 + lane] +
                      r_lds[(k2 * 4 + 3) * 64 + lane];
      if (active && ti >= own_i && tj >= own_j) {
        const int addr = ((b * OH + i0 + ti) * OW) + j0 + tj;
        if constexpr (PARTIAL)
          ws[PBASE + pack * E + addr] = v;  // exactly-once plain store
        else
          atomicAdd(ws + WS_CORR + START + addr, v);
      }
    }
  }
}

// ---------------- fused main kernel (partial path) --------------------------
// bid 0..767: L3 corr (4x4 tiles, 3 blocks/CU balanced); 768..831: L2;
// 832..863: L1; 864..879: L0; 880..1391: prep slices (tail-filling).
__global__ __launch_bounds__(256, 1) void fused_kernel(
    const float* g0, const float* s0, const float* m0, const float* g1,
    const float* s1, const float* m1, const float* g2, const float* s2,
    const float* m2, const float* g3, const float* s3, const float* m3,
    float* ws) {
  __shared__ float g_lds[4 * 416];
  __shared__ float r_lds[16 * 4 * 64];
  __shared__ float sw[4];
  const int bid = blockIdx.x;
  if (bid < 880) {
    const int wv = threadIdx.x >> 6;
    const int lane = threadIdx.x & 63;
    float* gl = g_lds + wv * 416;
    if (bid < 768)
      corr_level<true, PB3, 8, 128, 53, 38, 76, 4, 19, 361, 8, 8, 6, 16336>(
          bid, wv, lane, g3, s3, m3, ws, gl, r_lds);
    else if (bid < 832)
      corr_level<true, PB2, 16, 64, 26, 19, 39, 8, 5, 50, 8, 4, 1, 4168>(
          bid - 768, wv, lane, g2, s2, m2, ws, gl, r_lds);
    else if (bid < 864)
      corr_level<true, PB1, 32, 32, 13, 10, 20, 8, 3, 15, 16, 1, 1, 968>(
          bid - 832, wv, lane, g1, s1, m1, ws, gl, r_lds);
    else
      corr_level<true, PB0, 64, 16, 6, 5, 11, 8, 2, 6, 8, 1, 1, 0>(
          bid - 864, wv, lane, g0, s0, m0, ws, gl, r_lds);
  } else {
    const int pb = bid - 880;
    const int pair = pb >> 4;   // 0..31
    const int k = pb & 15;      // slice 0..15
    const int lev = pair >> 3;
    const int b = pair & 7;
    float* part = ws + WS_PART + (pair * 16 + k) * 2;
    if (lev == 0)      prep_partial_level<64, 16, 6, 5>(g0, s0, m0, b, k, part, sw);
    else if (lev == 1) prep_partial_level<32, 32, 13, 10>(g1, s1, m1, b, k, part, sw);
    else if (lev == 2) prep_partial_level<16, 64, 26, 19>(g2, s2, m2, b, k, part, sw);
    else               prep_partial_level<8, 128, 53, 38>(g3, s3, m3, b, k, part, sw);
  }
}

// ---------------- loss2 (partial path): sc + partial sums inline ------------
__global__ __launch_bounds__(256) void loss2_kernel(const float* __restrict__ u,
                                                    const float* __restrict__ v,
                                                    const float* __restrict__ hd,
                                                    float* __restrict__ ws) {
  __shared__ float sw[4];
  const int e = blockIdx.x * 256 + threadIdx.x;
  float term = 0.0f;
  if (e < N_ENTRIES) {
    int lev, start, OH, np, base, E;
    float mpp;
    if (e < 968)        { lev = 0; start = 0;     OH = 11; mpp = 6.4f; np = 2;  base = PB0; E = 968; }
    else if (e < 4168)  { lev = 1; start = 968;   OH = 20; mpp = 3.2f; np = 4;  base = PB1; E = 3200; }
    else if (e < 16336) { lev = 2; start = 4168;  OH = 39; mpp = 1.6f; np = 8;  base = PB2; E = 12168; }
    else                { lev = 3; start = 16336; OH = 76; mpp = 0.8f; np = 16; base = PB3; E = 46208; }
    const int r = e - start;
    const int ow2 = OH * OH;
    const int b = r / ow2;
    // sc inline (identical op order to the old prep_final_kernel)
    const float* p = ws + WS_PART + (lev * 8 + b) * 32;
    float s1 = 0.0f, s2 = 0.0f;
    for (int kk = 0; kk < 16; ++kk) {
      s1 += p[2 * kk];
      s2 += p[2 * kk + 1];
    }
    const float norm = sqrtf(s1);
    const float denom = fmaxf(sqrtf(s2 + 1e-8f), 1e-6f);
    const float scv = 2.0f / (fmaxf(norm, 1e-12f) * denom);
    // gt position, replicating the reference fp32 op order
    float t = hd[b] * 10.0f;
    t = t / 180.0f;
    t = t * 3.14159265358979323846f;
    const float cs = cosf(t), sn = sinf(t);
    const float gdx = -u[b] * 20.0f;
    const float gdy = -v[b] * 20.0f;
    const float dxr = -gdx * cs + gdy * sn;
    const float dyr = gdx * sn + gdy * cs;
    int wi = (int)rintf(OH * 0.5f - 0.5f + dxr / mpp);  // rintf = round-half-even
    int hi = (int)rintf(OH * 0.5f - 0.5f + dyr / mpp);
    wi = min(max(wi, 0), OH - 1);
    hi = min(max(hi, 0), OH - 1);
    const int posoff = (b * OH + hi) * OH + wi;
    // raw/rp: same summation order as the old reduce_kernel
    float raw = 0.0f, rp = 0.0f;
    for (int pp = 0; pp < np; ++pp) {
      raw += ws[base + pp * E + r];
      rp += ws[base + pp * E + posoff];
    }
    const float z = 10.0f * scv * (raw - rp);
    const float spl = fmaxf(z, 0.0f) + log1pf(expf(-fabsf(z)));
    term = spl / (8.0f * (float)(ow2 - 1));
  }
  const float tot = block_sum256(term, sw);
  if (threadIdx.x == 0) ws[WS_CORR + blockIdx.x] = tot;
}

// ---------------- final: deterministic 245-way sum -> out -------------------
__global__ __launch_bounds__(256) void final_kernel(const float* __restrict__ ws,
                                                    float* __restrict__ out) {
  __shared__ float sw[4];
  const int t = threadIdx.x;
  float v = (t < 245) ? ws[WS_CORR + t] : 0.0f;
  const float tot = block_sum256(v, sw);
  if (t == 0) out[0] = tot;
}

// ---------------- standalone corr (FALLBACK, atomic accumulate) -------------
__global__ __launch_bounds__(256, 1) void corr_kernel_fb(
    const float* g0, const float* s0, const float* m0, const float* g1,
    const float* s1, const float* m1, const float* g2, const float* s2,
    const float* m2, const float* g3, const float* s3, const float* m3,
    float* ws) {
  __shared__ float g_lds[4 * 416];
  __shared__ float r_lds[16 * 4 * 64];
  const int wv = threadIdx.x >> 6;
  const int lane = threadIdx.x & 63;
  float* gl = g_lds + wv * 416;
  const int bid = blockIdx.x;
  if (bid < 768)
    corr_level<false, PB3, 8, 128, 53, 38, 76, 4, 19, 361, 8, 8, 6, 16336>(
        bid, wv, lane, g3, s3, m3, ws, gl, r_lds);
  else if (bid < 832)
    corr_level<false, PB2, 16, 64, 26, 19, 39, 8, 5, 50, 8, 4, 1, 4168>(
        bid - 768, wv, lane, g2, s2, m2, ws, gl, r_lds);
  else if (bid < 864)
    corr_level<false, PB1, 32, 32, 13, 10, 20, 8, 3, 15, 16, 1, 1, 968>(
        bid - 832, wv, lane, g1, s1, m1, ws, gl, r_lds);
  else
    corr_level<false, PB0, 64, 16, 6, 5, 11, 8, 2, 6, 8, 1, 1, 0>(
        bid - 864, wv, lane, g0, s0, m0, ws, gl, r_lds);
}

// ---------------- loss (FALLBACK: reads reduced WS_CORR, atomic out) --------
__global__ __launch_bounds__(256) void loss_kernel(const float* __restrict__ u,
                                                   const float* __restrict__ v,
                                                   const float* __restrict__ hd,
                                                   const float* __restrict__ ws,
                                                   float* __restrict__ out) {
  __shared__ float sw[4];
  const int e = blockIdx.x * 256 + threadIdx.x;
  float term = 0.0f;
  if (e < N_ENTRIES) {
    int lev, start, OH;
    float mpp;
    if (e < 968)        { lev = 0; start = 0;     OH = 11; mpp = 6.4f; }
    else if (e < 4168)  { lev = 1; start = 968;   OH = 20; mpp = 3.2f; }
    else if (e < 16336) { lev = 2; start = 4168;  OH = 39; mpp = 1.6f; }
    else                { lev = 3; start = 16336; OH = 76; mpp = 0.8f; }
    const int r = e - start;
    const int ow2 = OH * OH;
    const int b = r / ow2;
    const float scv = ws[WS_SC + lev * 8 + b];
    float t = hd[b] * 10.0f;
    t = t / 180.0f;
    t = t * 3.14159265358979323846f;
    const float cs = cosf(t), sn = sinf(t);
    const float gdx = -u[b] * 20.0f;
    const float gdy = -v[b] * 20.0f;
    const float dxr = -gdx * cs + gdy * sn;
    const float dyr = gdx * sn + gdy * cs;
    int wi = (int)rintf(OH * 0.5f - 0.5f + dxr / mpp);
    int hi = (int)rintf(OH * 0.5f - 0.5f + dyr / mpp);
    wi = min(max(wi, 0), OH - 1);
    hi = min(max(hi, 0), OH - 1);
    const float raw = ws[WS_CORR + e];
    const float rp = ws[WS_CORR + start + (b * OH + hi) * OH + wi];
    const float z = 10.0f * scv * (raw - rp);
    const float spl = fmaxf(z, 0.0f) + log1pf(expf(-fabsf(z)));
    term = spl / (8.0f * (float)(ow2 - 1));
  }
  const float tot = block_sum256(term, sw);
  if (threadIdx.x == 0) atomicAdd(out, tot);
}

// ---------------------------------------------------------------------------
extern "C" void kernel_launch(void* const* d_in, const int* in_sizes, int n_in,
                              void* d_out, int out_size, void* d_ws,
                              size_t ws_size, hipStream_t stream) {
  const float* g0 = (const float*)d_in[0];
  const float* s0 = (const float*)d_in[1];
  const float* m0 = (const float*)d_in[2];
  const float* g1 = (const float*)d_in[3];
  const float* s1 = (const float*)d_in[4];
  const float* m1 = (const float*)d_in[5];
  const float* g2 = (const float*)d_in[6];
  const float* s2 = (const float*)d_in[7];
  const float* m2 = (const float*)d_in[8];
  const float* g3 = (const float*)d_in[9];
  const float* s3 = (const float*)d_in[10];
  const float* m3 = (const float*)d_in[11];
  const float* u  = (const float*)d_in[12];
  const float* v  = (const float*)d_in[13];
  const float* hd = (const float*)d_in[14];
  float* ws = (float*)d_ws;
  float* out = (float*)d_out;
  const bool use_partial = (ws_size >= (size_t)WS_NEED_BYTES);

  if (use_partial) {
    // 3 launches: fused(corr+prep) -> loss2 -> final. No fp atomics.
    fused_kernel<<<dim3(1392), dim3(256), 0, stream>>>(
        g0, s0, m0, g1, s1, m1, g2, s2, m2, g3, s3, m3, ws);
    loss2_kernel<<<dim3(245), dim3(256), 0, stream>>>(u, v, hd, ws);
    final_kernel<<<dim3(1), dim3(256), 0, stream>>>(ws, out);
  } else {
    init_kernel<<<dim3(245), dim3(256), 0, stream>>>(ws, out);
    prep_partial_kernel<<<dim3(512), dim3(256), 0, stream>>>(
        g0, s0, m0, g1, s1, m1, g2, s2, m2, g3, s3, m3, ws);
    prep_final_kernel<<<dim3(1), dim3(64), 0, stream>>>(ws);
    corr_kernel_fb<<<dim3(880), dim3(256), 0, stream>>>(
        g0, s0, m0, g1, s1, m1, g2, s2, m2, g3, s3, m3, ws);
    loss_kernel<<<dim3(245), dim3(256), 0, stream>>>(u, v, hd, ws, out);
  }
}

// Round 21
// 72.315 us; speedup vs baseline: 1.3269x; 1.3269x over previous
//
#include <hip/hip_runtime.h>
#include <math.h>

// ---------------------------------------------------------------------------
// MutilLocalLoss on MI355X.
// Level constants (match Python int()/round() semantics exactly):
//   lev: C,  A,  CROP, TOP, OH, TJ8, NTILES, CSPLIT, RSPLIT, CHUNKS, START
//   0:   64, 16,  6,    5,  11,  2,    6,     8,      1,      1,      0
//   1:   32, 32, 13,   10,  20,  3,   15,    16,      1,      1,    968
//   2:   16, 64, 26,   19,  39,  5,   50,     8,      4,      1,   4168
//   3:    8,128, 53,   38,  76, 10,  190,     8,      8,      3,  16336
// R3-R20 history: VALUBusy pinned 33-37% across ALL structural changes.
// Closed arithmetic (R20): per L3 r-iter, FMA issue ~2330cy vs ~9700cy
// elapsed; gap = 15 rbuf GLOBAL loads x ~500cy, SERIALIZED because
// rbuf+acc+addr >100 live floats vs VGPR=80 (compiler recycles load regs).
// R13/R20 (more blocks): worse. R14/R15 (filter-side pipeline): worse (pad
// FMAs). R19 (LDS slab): null (+conflicts). R21: sat-side rbuf DOUBLE
// BUFFER across r-loop -- rbA/rbB named arrays, hand-unrolled 2-step loop
// (static indices), zero extra FMAs. Loads for r+1 issue before r's FMAs.
// Geometry = R18 verbatim (best: 496 corr blocks, TJW=8).
// ws floats: [0,32) sc(fallback); [32,1056) prep parts; [1056,1056+245)
//            loss block sums (partial path) / corr final (fallback);
//            [63600,915008) per-pack corr partials (3.7MB; fallback else).
// ---------------------------------------------------------------------------

#define WS_SC 0
#define WS_PART 32
#define WS_CORR 1056
#define N_ENTRIES 62544
#define PB0 63600
#define PB1 65536
#define PB2 78336
#define PB3 175680
#define WS_NEED_BYTES 3700000

__device__ __forceinline__ float block_sum256(float v, float* sw) {
#pragma unroll
  for (int o = 32; o > 0; o >>= 1) v += __shfl_down(v, o, 64);
  if ((threadIdx.x & 63) == 0) sw[threadIdx.x >> 6] = v;
  __syncthreads();
  float r = (threadIdx.x < 4) ? sw[threadIdx.x] : 0.0f;
  r += __shfl_down(r, 2, 64);
  r += __shfl_down(r, 1, 64);
  __syncthreads();
  return r;  // total valid in thread 0
}

// ---------------- init: zero corr accumulators + out (FALLBACK only) --------
__global__ __launch_bounds__(256) void init_kernel(float* __restrict__ ws,
                                                   float* __restrict__ out) {
  const int e = blockIdx.x * 256 + threadIdx.x;
  if (e < N_ENTRIES) ws[WS_CORR + e] = 0.0f;
  if (e == 0) out[0] = 0.0f;
}

// ---------------- prep stage 1: 16-way sliced partial energies --------------
template <int C, int A, int CROP, int TOP>
__device__ void prep_partial_level(const float* __restrict__ grd,
                                   const float* __restrict__ sat,
                                   const float* __restrict__ mask, int b, int k,
                                   float* __restrict__ part, float* sw) {
  const float* gb = grd + (size_t)b * C * A * A;
  float s1 = 0.0f;
  constexpr int N1 = C * CROP * CROP;
  for (int idx = k * 256 + (int)threadIdx.x; idx < N1; idx += 4096) {
    int c = idx / (CROP * CROP);
    int r = idx - c * (CROP * CROP);
    int h = r / CROP;
    int w = r - h * CROP;
    float m = mask[(TOP + h) * A + (TOP + w)];
    float g = gb[((size_t)c * A + (TOP + h)) * A + (TOP + w)] * m;
    s1 += g * g;
  }
  s1 = block_sum256(s1, sw);
  const float4* sb = (const float4*)(sat + (size_t)b * C * A * A);
  const float4* m4 = (const float4*)mask;
  float s2 = 0.0f;
  constexpr int NV = C * A * A / 4;
  constexpr int MV = A * A / 4;
  for (int v = k * 256 + (int)threadIdx.x; v < NV; v += 4096) {
    float4 sv = sb[v];
    float4 mv = m4[v & (MV - 1)];
    s2 += sv.x * sv.x * mv.x + sv.y * sv.y * mv.y + sv.z * sv.z * mv.z +
          sv.w * sv.w * mv.w;
  }
  s2 = block_sum256(s2, sw);
  if (threadIdx.x == 0) {
    part[0] = s1;
    part[1] = s2;
  }
}

__global__ __launch_bounds__(256) void prep_partial_kernel(
    const float* g0, const float* s0, const float* m0, const float* g1,
    const float* s1, const float* m1, const float* g2, const float* s2,
    const float* m2, const float* g3, const float* s3, const float* m3,
    float* ws) {
  __shared__ float sw[4];
  const int pair = blockIdx.x >> 4;   // 0..31
  const int k = blockIdx.x & 15;      // slice 0..15
  const int lev = pair >> 3;
  const int b = pair & 7;
  float* part = ws + WS_PART + (pair * 16 + k) * 2;
  if (lev == 0)      prep_partial_level<64, 16, 6, 5>(g0, s0, m0, b, k, part, sw);
  else if (lev == 1) prep_partial_level<32, 32, 13, 10>(g1, s1, m1, b, k, part, sw);
  else if (lev == 2) prep_partial_level<16, 64, 26, 19>(g2, s2, m2, b, k, part, sw);
  else               prep_partial_level<8, 128, 53, 38>(g3, s3, m3, b, k, part, sw);
}

// ---------------- prep stage 2 (FALLBACK only) ------------------------------
__global__ __launch_bounds__(64) void prep_final_kernel(float* __restrict__ ws) {
  const int t = threadIdx.x;
  if (t < 32) {
    float s1 = 0.0f, s2 = 0.0f;
    const float* p = ws + WS_PART + t * 32;
    for (int k = 0; k < 16; ++k) {
      s1 += p[2 * k];
      s2 += p[2 * k + 1];
    }
    float norm = sqrtf(s1);
    float denom = fmaxf(sqrtf(s2 + 1e-8f), 1e-6f);
    ws[WS_SC + t] = 2.0f / (fmaxf(norm, 1e-12f) * denom);
  }
}

// ---- rbuf load + compute macros (textual; capture enclosing locals) --------
#define LOADRB(RB, RR)                                                       \
  {                                                                          \
    const float* srow_ = satc + (size_t)(RR)*A;                              \
    _Pragma("unroll") for (int k_ = 0; k_ < NV8 - 1; ++k_) {                 \
      float4 t_ = *(const float4*)(srow_ + 4 * k_);                          \
      RB[4 * k_ + 0] = t_.x;                                                 \
      RB[4 * k_ + 1] = t_.y;                                                 \
      RB[4 * k_ + 2] = t_.z;                                                 \
      RB[4 * k_ + 3] = t_.w;                                                 \
    }                                                                        \
    _Pragma("unroll") for (int q_ = 0; q_ < TAIL; ++q_) {                    \
      const int idx_ = 4 * (NV8 - 1) + q_;                                   \
      RB[idx_] = (idx_ <= amax) ? srow_[idx_] : 0.0f;                        \
    }                                                                        \
  }

#define COMPUTE(RB, RR)                                                      \
  _Pragma("unroll") for (int ti_ = 0; ti_ < 4; ++ti_) {                      \
    const int h_ = (RR)-ti_;                                                 \
    if ((unsigned)h_ < (unsigned)nr) {                                       \
      const float* grow_ = gl + h_ * RS4;                                    \
      _Pragma("unroll") for (int w4_ = 0; w4_ < RS4 / 4; ++w4_) {            \
        const float4 gq_ = *(const float4*)(grow_ + 4 * w4_);                \
        _Pragma("unroll") for (int gi_ = 0; gi_ < 4; ++gi_) {                \
          const int w_ = 4 * w4_ + gi_;                                      \
          if (w_ < CROP) {                                                   \
            const float g_ = (gi_ == 0)   ? gq_.x                            \
                             : (gi_ == 1) ? gq_.y                            \
                             : (gi_ == 2) ? gq_.z                            \
                                          : gq_.w;                           \
            _Pragma("unroll") for (int tj_ = 0; tj_ < 8; ++tj_)              \
                acc[ti_][tj_] = fmaf(RB[w_ + tj_], g_, acc[ti_][tj_]);       \
          }                                                                  \
        }                                                                    \
      }                                                                      \
    }                                                                        \
  }

// ---------------- corr: 4x8-tile partials, rbuf DOUBLE-BUFFERED -------------
template <bool PARTIAL, int PBASE, int C, int A, int CROP, int TOP, int OH,
          int TJ8, int NTILES, int CSPLIT, int RSPLIT, int CHUNKS, int START>
__device__ void corr_level(int rel, int wv, int lane,
                           const float* __restrict__ grd,
                           const float* __restrict__ sat,
                           const float* __restrict__ mask,
                           float* __restrict__ ws, float* g_lds,
                           float* r_lds) {
  constexpr int CSP = C / CSPLIT;
  constexpr int OW = OH;
  constexpr int RS4 = (CROP + 3) & ~3;          // padded filter row (floats)
  constexpr int NV8 = (CROP + 7 + 3) / 4;       // quads covering CROP+7 span
  constexpr int TAIL = CROP + 7 - 4 * (NV8 - 1);  // 1..4 tail elements
  constexpr int NPACK = CSPLIT * RSPLIT / 4;
  constexpr int E = 8 * OH * OW;
  // rel -> (b, chunk, pack); wave wv covers slice pack*4+wv
  const int b = rel / (CHUNKS * NPACK);
  int r2 = rel - b * (CHUNKS * NPACK);
  const int chunk = r2 / NPACK;
  const int pack = r2 - chunk * NPACK;
  const int sl = pack * 4 + wv;
  const int cs = sl / RSPLIT;
  const int rs = sl - cs * RSPLIT;
  const int c0 = cs * CSP;
  const int r0 = (rs * CROP) / RSPLIT;          // filter-row slice [r0, r1)
  const int r1 = ((rs + 1) * CROP) / RSPLIT;
  const int nr = r1 - r0;

  // stage masked filter slice, rows padded to RS4, pad zeroed (<=416 floats)
  const float* gb = grd + (size_t)(b * C + c0) * A * A;
  for (int c = 0; c < CSP; ++c)
    for (int h = 0; h < nr; ++h)
      if (lane < RS4)
        g_lds[(c * nr + h) * RS4 + lane] =
            (lane < CROP)
                ? gb[((size_t)c * A + (TOP + r0 + h)) * A + (TOP + lane)] *
                      mask[(TOP + r0 + h) * A + (TOP + lane)]
                : 0.0f;
  __syncthreads();

  const int s = chunk * 64 + lane;
  const bool active = s < NTILES;
  const int ss = active ? s : chunk * 64;
  const int ii = ss / TJ8;
  const int jj = ss - ii * TJ8;
  const int i0 = min(ii * 4, OH - 4);   // clamp; ownership masks below
  const int j0 = min(jj * 8, OW - 8);
  const int own_i = ii * 4 - i0;
  const int own_j = jj * 8 - j0;
  const int amax = A - 1 - j0;          // last valid srow index

  float acc[4][8] = {};
  const float* sb =
      sat + (size_t)(b * C + c0) * A * A + (size_t)(i0 + r0) * A + j0;
#pragma unroll 1
  for (int c = 0; c < CSP; ++c) {
    const float* satc = sb + (size_t)c * A * A;
    const float* gl = g_lds + c * nr * RS4;
    const int rend = nr + 3;
    float rbA[NV8 * 4], rbB[NV8 * 4];
    // software pipeline: rbX holds row r's window while r+1 loads into rbY.
    LOADRB(rbA, 0);
    int r = 0;
    for (;;) {
      if (r + 1 < rend) LOADRB(rbB, r + 1);
      COMPUTE(rbA, r);
      ++r;
      if (r >= rend) break;
      if (r + 1 < rend) LOADRB(rbA, r + 1);
      COMPUTE(rbB, r);
      ++r;
      if (r >= rend) break;
    }
  }

  // --- block reduction: 4 waves hold partials for the SAME tile map -------
  // 32 accs merged in two 16-slice passes through r_lds[16][4][64] (16KB).
#pragma unroll
  for (int p = 0; p < 2; ++p) {
    if (p) __syncthreads();
#pragma unroll
    for (int k2 = 0; k2 < 16; ++k2) {
      const int gk = p * 16 + k2;
      r_lds[(k2 * 4 + wv) * 64 + lane] = acc[gk >> 3][gk & 7];
    }
    __syncthreads();
#pragma unroll
    for (int kk = 0; kk < 4; ++kk) {
      const int k2 = wv * 4 + kk;
      const int gk = p * 16 + k2;
      const int ti = gk >> 3;
      const int tj = gk & 7;
      const float v = r_lds[(k2 * 4 + 0) * 64 + lane] +
                      r_lds[(k2 * 4 + 1) * 64 + lane] +
                      r_lds[(k2 * 4 + 2) * 64 + lane] +
                      r_lds[(k2 * 4 + 3) * 64 + lane];
      if (active && ti >= own_i && tj >= own_j) {
        const int addr = ((b * OH + i0 + ti) * OW) + j0 + tj;
        if constexpr (PARTIAL)
          ws[PBASE + pack * E + addr] = v;  // exactly-once plain store
        else
          atomicAdd(ws + WS_CORR + START + addr, v);
      }
    }
  }
}

// ---------------- fused main kernel (partial path) --------------------------
// bid 0..495: corr (L3-first, R18 geometry); bid 496..1007: prep slices.
__global__ __launch_bounds__(256, 1) void fused_kernel(
    const float* g0, const float* s0, const float* m0, const float* g1,
    const float* s1, const float* m1, const float* g2, const float* s2,
    const float* m2, const float* g3, const float* s3, const float* m3,
    float* ws) {
  __shared__ float g_lds[4 * 416];
  __shared__ float r_lds[16 * 4 * 64];
  __shared__ float sw[4];
  const int bid = blockIdx.x;
  if (bid < 496) {
    const int wv = threadIdx.x >> 6;
    const int lane = threadIdx.x & 63;
    float* gl = g_lds + wv * 416;
    if (bid < 384)
      corr_level<true, PB3, 8, 128, 53, 38, 76, 10, 190, 8, 8, 3, 16336>(
          bid, wv, lane, g3, s3, m3, ws, gl, r_lds);
    else if (bid < 448)
      corr_level<true, PB2, 16, 64, 26, 19, 39, 5, 50, 8, 4, 1, 4168>(
          bid - 384, wv, lane, g2, s2, m2, ws, gl, r_lds);
    else if (bid < 480)
      corr_level<true, PB1, 32, 32, 13, 10, 20, 3, 15, 16, 1, 1, 968>(
          bid - 448, wv, lane, g1, s1, m1, ws, gl, r_lds);
    else
      corr_level<true, PB0, 64, 16, 6, 5, 11, 2, 6, 8, 1, 1, 0>(
          bid - 480, wv, lane, g0, s0, m0, ws, gl, r_lds);
  } else {
    const int pb = bid - 496;
    const int pair = pb >> 4;   // 0..31
    const int k = pb & 15;      // slice 0..15
    const int lev = pair >> 3;
    const int b = pair & 7;
    float* part = ws + WS_PART + (pair * 16 + k) * 2;
    if (lev == 0)      prep_partial_level<64, 16, 6, 5>(g0, s0, m0, b, k, part, sw);
    else if (lev == 1) prep_partial_level<32, 32, 13, 10>(g1, s1, m1, b, k, part, sw);
    else if (lev == 2) prep_partial_level<16, 64, 26, 19>(g2, s2, m2, b, k, part, sw);
    else               prep_partial_level<8, 128, 53, 38>(g3, s3, m3, b, k, part, sw);
  }
}

// ---------------- loss2 (partial path): sc + partial sums inline ------------
__global__ __launch_bounds__(256) void loss2_kernel(const float* __restrict__ u,
                                                    const float* __restrict__ v,
                                                    const float* __restrict__ hd,
                                                    float* __restrict__ ws) {
  __shared__ float sw[4];
  const int e = blockIdx.x * 256 + threadIdx.x;
  float term = 0.0f;
  if (e < N_ENTRIES) {
    int lev, start, OH, np, base, E;
    float mpp;
    if (e < 968)        { lev = 0; start = 0;     OH = 11; mpp = 6.4f; np = 2;  base = PB0; E = 968; }
    else if (e < 4168)  { lev = 1; start = 968;   OH = 20; mpp = 3.2f; np = 4;  base = PB1; E = 3200; }
    else if (e < 16336) { lev = 2; start = 4168;  OH = 39; mpp = 1.6f; np = 8;  base = PB2; E = 12168; }
    else                { lev = 3; start = 16336; OH = 76; mpp = 0.8f; np = 16; base = PB3; E = 46208; }
    const int r = e - start;
    const int ow2 = OH * OH;
    const int b = r / ow2;
    // sc inline (identical op order to the old prep_final_kernel)
    const float* p = ws + WS_PART + (lev * 8 + b) * 32;
    float s1 = 0.0f, s2 = 0.0f;
    for (int kk = 0; kk < 16; ++kk) {
      s1 += p[2 * kk];
      s2 += p[2 * kk + 1];
    }
    const float norm = sqrtf(s1);
    const float denom = fmaxf(sqrtf(s2 + 1e-8f), 1e-6f);
    const float scv = 2.0f / (fmaxf(norm, 1e-12f) * denom);
    // gt position, replicating the reference fp32 op order
    float t = hd[b] * 10.0f;
    t = t / 180.0f;
    t = t * 3.14159265358979323846f;
    const float cs = cosf(t), sn = sinf(t);
    const float gdx = -u[b] * 20.0f;
    const float gdy = -v[b] * 20.0f;
    const float dxr = -gdx * cs + gdy * sn;
    const float dyr = gdx * sn + gdy * cs;
    int wi = (int)rintf(OH * 0.5f - 0.5f + dxr / mpp);  // rintf = round-half-even
    int hi = (int)rintf(OH * 0.5f - 0.5f + dyr / mpp);
    wi = min(max(wi, 0), OH - 1);
    hi = min(max(hi, 0), OH - 1);
    const int posoff = (b * OH + hi) * OH + wi;
    // raw/rp: same summation order as the old reduce_kernel
    float raw = 0.0f, rp = 0.0f;
    for (int pp = 0; pp < np; ++pp) {
      raw += ws[base + pp * E + r];
      rp += ws[base + pp * E + posoff];
    }
    const float z = 10.0f * scv * (raw - rp);
    const float spl = fmaxf(z, 0.0f) + log1pf(expf(-fabsf(z)));
    term = spl / (8.0f * (float)(ow2 - 1));
  }
  const float tot = block_sum256(term, sw);
  if (threadIdx.x == 0) ws[WS_CORR + blockIdx.x] = tot;
}

// ---------------- final: deterministic 245-way sum -> out -------------------
__global__ __launch_bounds__(256) void final_kernel(const float* __restrict__ ws,
                                                    float* __restrict__ out) {
  __shared__ float sw[4];
  const int t = threadIdx.x;
  float v = (t < 245) ? ws[WS_CORR + t] : 0.0f;
  const float tot = block_sum256(v, sw);
  if (t == 0) out[0] = tot;
}

// ---------------- standalone corr (FALLBACK, atomic accumulate) -------------
__global__ __launch_bounds__(256, 1) void corr_kernel_fb(
    const float* g0, const float* s0, const float* m0, const float* g1,
    const float* s1, const float* m1, const float* g2, const float* s2,
    const float* m2, const float* g3, const float* s3, const float* m3,
    float* ws) {
  __shared__ float g_lds[4 * 416];
  __shared__ float r_lds[16 * 4 * 64];
  const int wv = threadIdx.x >> 6;
  const int lane = threadIdx.x & 63;
  float* gl = g_lds + wv * 416;
  const int bid = blockIdx.x;
  if (bid < 384)
    corr_level<false, PB3, 8, 128, 53, 38, 76, 10, 190, 8, 8, 3, 16336>(
        bid, wv, lane, g3, s3, m3, ws, gl, r_lds);
  else if (bid < 448)
    corr_level<false, PB2, 16, 64, 26, 19, 39, 5, 50, 8, 4, 1, 4168>(
        bid - 384, wv, lane, g2, s2, m2, ws, gl, r_lds);
  else if (bid < 480)
    corr_level<false, PB1, 32, 32, 13, 10, 20, 3, 15, 16, 1, 1, 968>(
        bid - 448, wv, lane, g1, s1, m1, ws, gl, r_lds);
  else
    corr_level<false, PB0, 64, 16, 6, 5, 11, 2, 6, 8, 1, 1, 0>(
        bid - 480, wv, lane, g0, s0, m0, ws, gl, r_lds);
}

// ---------------- loss (FALLBACK: reads reduced WS_CORR, atomic out) --------
__global__ __launch_bounds__(256) void loss_kernel(const float* __restrict__ u,
                                                   const float* __restrict__ v,
                                                   const float* __restrict__ hd,
                                                   const float* __restrict__ ws,
                                                   float* __restrict__ out) {
  __shared__ float sw[4];
  const int e = blockIdx.x * 256 + threadIdx.x;
  float term = 0.0f;
  if (e < N_ENTRIES) {
    int lev, start, OH;
    float mpp;
    if (e < 968)        { lev = 0; start = 0;     OH = 11; mpp = 6.4f; }
    else if (e < 4168)  { lev = 1; start = 968;   OH = 20; mpp = 3.2f; }
    else if (e < 16336) { lev = 2; start = 4168;  OH = 39; mpp = 1.6f; }
    else                { lev = 3; start = 16336; OH = 76; mpp = 0.8f; }
    const int r = e - start;
    const int ow2 = OH * OH;
    const int b = r / ow2;
    const float scv = ws[WS_SC + lev * 8 + b];
    float t = hd[b] * 10.0f;
    t = t / 180.0f;
    t = t * 3.14159265358979323846f;
    const float cs = cosf(t), sn = sinf(t);
    const float gdx = -u[b] * 20.0f;
    const float gdy = -v[b] * 20.0f;
    const float dxr = -gdx * cs + gdy * sn;
    const float dyr = gdx * sn + gdy * cs;
    int wi = (int)rintf(OH * 0.5f - 0.5f + dxr / mpp);
    int hi = (int)rintf(OH * 0.5f - 0.5f + dyr / mpp);
    wi = min(max(wi, 0), OH - 1);
    hi = min(max(hi, 0), OH - 1);
    const float raw = ws[WS_CORR + e];
    const float rp = ws[WS_CORR + start + (b * OH + hi) * OH + wi];
    const float z = 10.0f * scv * (raw - rp);
    const float spl = fmaxf(z, 0.0f) + log1pf(expf(-fabsf(z)));
    term = spl / (8.0f * (float)(ow2 - 1));
  }
  const float tot = block_sum256(term, sw);
  if (threadIdx.x == 0) atomicAdd(out, tot);
}

// ---------------------------------------------------------------------------
extern "C" void kernel_launch(void* const* d_in, const int* in_sizes, int n_in,
                              void* d_out, int out_size, void* d_ws,
                              size_t ws_size, hipStream_t stream) {
  const float* g0 = (const float*)d_in[0];
  const float* s0 = (const float*)d_in[1];
  const float* m0 = (const float*)d_in[2];
  const float* g1 = (const float*)d_in[3];
  const float* s1 = (const float*)d_in[4];
  const float* m1 = (const float*)d_in[5];
  const float* g2 = (const float*)d_in[6];
  const float* s2 = (const float*)d_in[7];
  const float* m2 = (const float*)d_in[8];
  const float* g3 = (const float*)d_in[9];
  const float* s3 = (const float*)d_in[10];
  const float* m3 = (const float*)d_in[11];
  const float* u  = (const float*)d_in[12];
  const float* v  = (const float*)d_in[13];
  const float* hd = (const float*)d_in[14];
  float* ws = (float*)d_ws;
  float* out = (float*)d_out;
  const bool use_partial = (ws_size >= (size_t)WS_NEED_BYTES);

  if (use_partial) {
    // 3 launches: fused(corr+prep) -> loss2 -> final. No fp atomics.
    fused_kernel<<<dim3(1008), dim3(256), 0, stream>>>(
        g0, s0, m0, g1, s1, m1, g2, s2, m2, g3, s3, m3, ws);
    loss2_kernel<<<dim3(245), dim3(256), 0, stream>>>(u, v, hd, ws);
    final_kernel<<<dim3(1), dim3(256), 0, stream>>>(ws, out);
  } else {
    init_kernel<<<dim3(245), dim3(256), 0, stream>>>(ws, out);
    prep_partial_kernel<<<dim3(512), dim3(256), 0, stream>>>(
        g0, s0, m0, g1, s1, m1, g2, s2, m2, g3, s3, m3, ws);
    prep_final_kernel<<<dim3(1), dim3(64), 0, stream>>>(ws);
    corr_kernel_fb<<<dim3(496), dim3(256), 0, stream>>>(
        g0, s0, m0, g1, s1, m1, g2, s2, m2, g3, s3, m3, ws);
    loss_kernel<<<dim3(245), dim3(256), 0, stream>>>(u, v, hd, ws, out);
  }
}

// Round 22
// 69.268 us; speedup vs baseline: 1.3853x; 1.0440x over previous
//
#include <hip/hip_runtime.h>
#include <math.h>

// ---------------------------------------------------------------------------
// MutilLocalLoss on MI355X. FINAL CONSOLIDATION = R19 verbatim (best: 71.1µs).
// Level constants (match Python int()/round() semantics exactly):
//   lev: C,  A,  CROP, TOP, OH, TJ8, NTILES, CSPLIT, RSPLIT, CHUNKS, START
//   0:   64, 16,  6,    5,  11,  2,    6,     8,      1,      1,      0
//   1:   32, 32, 13,   10,  20,  3,   15,    16,      1,      1,    968
//   2:   16, 64, 26,   19,  39,  5,   50,     8,      4,      1,   4168
//   3:    8,128, 53,   38,  76, 10,  190,     8,      8,      3,  16336
// Session summary (R3-R21): 311 -> 71.1µs. Wins: prep parallelization (R3),
// wave supply (R4), 4x4->4x8 tiles (R8/R11), block-merged outputs (R9),
// fused pipeline + deterministic reduction (R16/R18). Falsified theories:
// atomics (R10), VGPR cap (R12), block count (R13/R20), filter pipeline
// (R14/15), TA gather (R19 null), sat dbuf (R21: VGPR 136 but occupancy
// 17->10%, SLOWER). Equilibrium: ~35% duty x ~1.4 waves/SIMD; every
// HIP-source perturbation measured downhill. Remaining lever = inline-asm
// counted s_waitcnt batching (not validated in this loop).
// ws floats: [0,32) sc(fallback); [32,1056) prep parts; [1056,1056+245)
//            loss block sums (partial path) / corr final (fallback);
//            [63600,915008) per-pack corr partials (3.7MB; fallback else).
// ---------------------------------------------------------------------------

#define WS_SC 0
#define WS_PART 32
#define WS_CORR 1056
#define N_ENTRIES 62544
#define PB0 63600
#define PB1 65536
#define PB2 78336
#define PB3 175680
#define WS_NEED_BYTES 3700000

__device__ __forceinline__ float block_sum256(float v, float* sw) {
#pragma unroll
  for (int o = 32; o > 0; o >>= 1) v += __shfl_down(v, o, 64);
  if ((threadIdx.x & 63) == 0) sw[threadIdx.x >> 6] = v;
  __syncthreads();
  float r = (threadIdx.x < 4) ? sw[threadIdx.x] : 0.0f;
  r += __shfl_down(r, 2, 64);
  r += __shfl_down(r, 1, 64);
  __syncthreads();
  return r;  // total valid in thread 0
}

// ---------------- init: zero corr accumulators + out (FALLBACK only) --------
__global__ __launch_bounds__(256) void init_kernel(float* __restrict__ ws,
                                                   float* __restrict__ out) {
  const int e = blockIdx.x * 256 + threadIdx.x;
  if (e < N_ENTRIES) ws[WS_CORR + e] = 0.0f;
  if (e == 0) out[0] = 0.0f;
}

// ---------------- prep stage 1: 16-way sliced partial energies --------------
template <int C, int A, int CROP, int TOP>
__device__ void prep_partial_level(const float* __restrict__ grd,
                                   const float* __restrict__ sat,
                                   const float* __restrict__ mask, int b, int k,
                                   float* __restrict__ part, float* sw) {
  const float* gb = grd + (size_t)b * C * A * A;
  float s1 = 0.0f;
  constexpr int N1 = C * CROP * CROP;
  for (int idx = k * 256 + (int)threadIdx.x; idx < N1; idx += 4096) {
    int c = idx / (CROP * CROP);
    int r = idx - c * (CROP * CROP);
    int h = r / CROP;
    int w = r - h * CROP;
    float m = mask[(TOP + h) * A + (TOP + w)];
    float g = gb[((size_t)c * A + (TOP + h)) * A + (TOP + w)] * m;
    s1 += g * g;
  }
  s1 = block_sum256(s1, sw);
  const float4* sb = (const float4*)(sat + (size_t)b * C * A * A);
  const float4* m4 = (const float4*)mask;
  float s2 = 0.0f;
  constexpr int NV = C * A * A / 4;
  constexpr int MV = A * A / 4;
  for (int v = k * 256 + (int)threadIdx.x; v < NV; v += 4096) {
    float4 sv = sb[v];
    float4 mv = m4[v & (MV - 1)];
    s2 += sv.x * sv.x * mv.x + sv.y * sv.y * mv.y + sv.z * sv.z * mv.z +
          sv.w * sv.w * mv.w;
  }
  s2 = block_sum256(s2, sw);
  if (threadIdx.x == 0) {
    part[0] = s1;
    part[1] = s2;
  }
}

__global__ __launch_bounds__(256) void prep_partial_kernel(
    const float* g0, const float* s0, const float* m0, const float* g1,
    const float* s1, const float* m1, const float* g2, const float* s2,
    const float* m2, const float* g3, const float* s3, const float* m3,
    float* ws) {
  __shared__ float sw[4];
  const int pair = blockIdx.x >> 4;   // 0..31
  const int k = blockIdx.x & 15;      // slice 0..15
  const int lev = pair >> 3;
  const int b = pair & 7;
  float* part = ws + WS_PART + (pair * 16 + k) * 2;
  if (lev == 0)      prep_partial_level<64, 16, 6, 5>(g0, s0, m0, b, k, part, sw);
  else if (lev == 1) prep_partial_level<32, 32, 13, 10>(g1, s1, m1, b, k, part, sw);
  else if (lev == 2) prep_partial_level<16, 64, 26, 19>(g2, s2, m2, b, k, part, sw);
  else               prep_partial_level<8, 128, 53, 38>(g3, s3, m3, b, k, part, sw);
}

// ---------------- prep stage 2 (FALLBACK only) ------------------------------
__global__ __launch_bounds__(64) void prep_final_kernel(float* __restrict__ ws) {
  const int t = threadIdx.x;
  if (t < 32) {
    float s1 = 0.0f, s2 = 0.0f;
    const float* p = ws + WS_PART + t * 32;
    for (int k = 0; k < 16; ++k) {
      s1 += p[2 * k];
      s2 += p[2 * k + 1];
    }
    float norm = sqrtf(s1);
    float denom = fmaxf(sqrtf(s2 + 1e-8f), 1e-6f);
    ws[WS_SC + t] = 2.0f / (fmaxf(norm, 1e-12f) * denom);
  }
}

// ---------------- corr: 4x8-tile partials; SLAB = LDS-staged sat (L3) -------
// smem layout (floats): [0,4224) slab (4 waves x 1056) ALIASED with
// r_lds[0,4096) (barrier-separated); [4224,5888) g_lds (4 waves x 416).
template <bool PARTIAL, bool SLAB, int PBASE, int C, int A, int CROP, int TOP,
          int OH, int TJ8, int NTILES, int CSPLIT, int RSPLIT, int CHUNKS,
          int START>
__device__ void corr_level(int rel, int wv, int lane,
                           const float* __restrict__ grd,
                           const float* __restrict__ sat,
                           const float* __restrict__ mask,
                           float* __restrict__ ws, float* g_lds,
                           float* r_lds, float* slab) {
  constexpr int CSP = C / CSPLIT;
  constexpr int OW = OH;
  constexpr int RS4 = (CROP + 3) & ~3;          // padded filter row (floats)
  constexpr int NV8 = (CROP + 7 + 3) / 4;       // quads covering CROP+7 span
  constexpr int TAIL = CROP + 7 - 4 * (NV8 - 1);  // 1..4 tail elements
  constexpr int NPACK = CSPLIT * RSPLIT / 4;
  constexpr int E = 8 * OH * OW;
  constexpr int SA = 132;                        // slab row stride (L3 only)
  // rel -> (b, chunk, pack); wave wv covers slice pack*4+wv
  const int b = rel / (CHUNKS * NPACK);
  int r2 = rel - b * (CHUNKS * NPACK);
  const int chunk = r2 / NPACK;
  const int pack = r2 - chunk * NPACK;
  const int sl = pack * 4 + wv;
  const int cs = sl / RSPLIT;
  const int rs = sl - cs * RSPLIT;
  const int c0 = cs * CSP;
  const int r0 = (rs * CROP) / RSPLIT;          // filter-row slice [r0, r1)
  const int r1 = ((rs + 1) * CROP) / RSPLIT;
  const int nr = r1 - r0;

  // stage masked filter slice, rows padded to RS4, pad zeroed (<=416 floats)
  const float* gb = grd + (size_t)(b * C + c0) * A * A;
  for (int c = 0; c < CSP; ++c)
    for (int h = 0; h < nr; ++h)
      if (lane < RS4)
        g_lds[(c * nr + h) * RS4 + lane] =
            (lane < CROP)
                ? gb[((size_t)c * A + (TOP + r0 + h)) * A + (TOP + lane)] *
                      mask[(TOP + r0 + h) * A + (TOP + lane)]
                : 0.0f;
  __syncthreads();

  const int s = chunk * 64 + lane;
  const bool active = s < NTILES;
  const int ss = active ? s : chunk * 64;  // inactive -> first tile of chunk
  const int ii = ss / TJ8;
  const int jj = ss - ii * TJ8;
  const int i0 = min(ii * 4, OH - 4);   // clamp; ownership masks below
  const int j0 = min(jj * 8, OW - 8);
  const int own_i = ii * 4 - i0;
  const int own_j = jj * 8 - j0;
  const int amax = A - 1 - j0;          // last valid srow index
  const int iiBase = (chunk * 64) / TJ8;  // SLAB: first ii-group of chunk
  const int glane = ii - iiBase;          // SLAB: this lane's slab row

  float acc[4][8] = {};
  const float* satBase = sat + (size_t)(b * C + c0) * A * A;
  const float* sb = satBase + (size_t)(i0 + r0) * A + j0;
#pragma unroll 1
  for (int c = 0; c < CSP; ++c) {
    const float* satc0 = satBase + (size_t)c * A * A;
    const float* gl = g_lds + c * nr * RS4;
#pragma unroll 1
    for (int r = 0; r < nr + 3; ++r) {
      float rbuf[NV8 * 4];
      if constexpr (SLAB) {
        // cooperative stage: NG=8 full sat rows -> wave-private slab.
        // idx 0..255 = 8 rows x 32 quads; coalesced dwordx4 per half-wave.
#pragma unroll
        for (int t = 0; t < 4; ++t) {
          const int idx = t * 64 + lane;
          const int g = idx >> 5;
          const int c4 = (idx & 31) << 2;
          const int rowabs = min(4 * (iiBase + g), OH - 4) + r0 + r;
          *(float4*)(slab + g * SA + c4) =
              *(const float4*)(satc0 + (size_t)rowabs * A + c4);
        }
        // rbuf from slab: 15 aligned ds_read_b128 (j0 % 4 == 0 for L3).
        const float* srow_l = slab + glane * SA + j0;
#pragma unroll
        for (int k = 0; k < NV8; ++k) {
          float4 t4 = *(const float4*)(srow_l + 4 * k);
          rbuf[4 * k + 0] = t4.x;
          rbuf[4 * k + 1] = t4.y;
          rbuf[4 * k + 2] = t4.z;
          rbuf[4 * k + 3] = t4.w;
        }
      } else {
        const float* srow = sb + (size_t)c * A * A + (size_t)r * A;
#pragma unroll
        for (int k = 0; k < NV8 - 1; ++k) {  // provably in-bounds
          float4 t = *(const float4*)(srow + 4 * k);
          rbuf[4 * k + 0] = t.x;
          rbuf[4 * k + 1] = t.y;
          rbuf[4 * k + 2] = t.z;
          rbuf[4 * k + 3] = t.w;
        }
#pragma unroll
        for (int q = 0; q < TAIL; ++q) {   // predicated tail, true positions
          const int idx = 4 * (NV8 - 1) + q;
          rbuf[idx] = (idx <= amax) ? srow[idx] : 0.0f;
        }
      }
#pragma unroll
      for (int ti = 0; ti < 4; ++ti) {
        const int h = r - ti;  // filter row for output row i0+ti
        if ((unsigned)h < (unsigned)nr) {  // wave-uniform guard
          const float* grow = gl + h * RS4;
#pragma unroll
          for (int w4 = 0; w4 < RS4 / 4; ++w4) {
            const float4 gq = *(const float4*)(grow + 4 * w4);  // ds_read_b128
#pragma unroll
            for (int gi = 0; gi < 4; ++gi) {
              const int w = 4 * w4 + gi;
              if (w < CROP) {  // compile-time: pad lanes dropped
                const float g = (gi == 0) ? gq.x : (gi == 1) ? gq.y
                                : (gi == 2) ? gq.z : gq.w;
#pragma unroll
                for (int tj = 0; tj < 8; ++tj)
                  acc[ti][tj] = fmaf(rbuf[w + tj], g, acc[ti][tj]);
              }
            }
          }
        }
      }
    }
  }

  // --- block reduction: 4 waves hold partials for the SAME tile map -------
  // 32 accs merged in two 16-slice passes through r_lds[16][4][64] (16KB).
  // Barrier before EACH pass's writes: r_lds aliases slab (SLAB path).
#pragma unroll
  for (int p = 0; p < 2; ++p) {
    __syncthreads();
#pragma unroll
    for (int k2 = 0; k2 < 16; ++k2) {
      const int gk = p * 16 + k2;
      r_lds[(k2 * 4 + wv) * 64 + lane] = acc[gk >> 3][gk & 7];
    }
    __syncthreads();
#pragma unroll
    for (int kk = 0; kk < 4; ++kk) {
      const int k2 = wv * 4 + kk;
      const int gk = p * 16 + k2;
      const int ti = gk >> 3;
      const int tj = gk & 7;
      const float v = r_lds[(k2 * 4 + 0) * 64 + lane] +
                      r_lds[(k2 * 4 + 1) * 64 + lane] +
                      r_lds[(k2 * 4 + 2) * 64 + lane] +
                      r_lds[(k2 * 4 + 3) * 64 + lane];
      if (active && ti >= own_i && tj >= own_j) {
        const int addr = ((b * OH + i0 + ti) * OW) + j0 + tj;
        if constexpr (PARTIAL)
          ws[PBASE + pack * E + addr] = v;  // exactly-once plain store
        else
          atomicAdd(ws + WS_CORR + START + addr, v);
      }
    }
  }
}

// ---------------- fused main kernel (partial path) --------------------------
// bid 0..495: corr (L3-first, R12 geometry, L3 SLAB); bid 496..1007: prep.
__global__ __launch_bounds__(256, 1) void fused_kernel(
    const float* g0, const float* s0, const float* m0, const float* g1,
    const float* s1, const float* m1, const float* g2, const float* s2,
    const float* m2, const float* g3, const float* s3, const float* m3,
    float* ws) {
  __shared__ float smem[5888];
  __shared__ float sw[4];
  const int bid = blockIdx.x;
  if (bid < 496) {
    const int wv = threadIdx.x >> 6;
    const int lane = threadIdx.x & 63;
    float* slab = smem + wv * 1056;
    float* gl = smem + 4224 + wv * 416;
    float* r_lds = smem;  // aliased with slab; barrier-separated
    if (bid < 384)
      corr_level<true, true, PB3, 8, 128, 53, 38, 76, 10, 190, 8, 8, 3, 16336>(
          bid, wv, lane, g3, s3, m3, ws, gl, r_lds, slab);
    else if (bid < 448)
      corr_level<true, false, PB2, 16, 64, 26, 19, 39, 5, 50, 8, 4, 1, 4168>(
          bid - 384, wv, lane, g2, s2, m2, ws, gl, r_lds, slab);
    else if (bid < 480)
      corr_level<true, false, PB1, 32, 32, 13, 10, 20, 3, 15, 16, 1, 1, 968>(
          bid - 448, wv, lane, g1, s1, m1, ws, gl, r_lds, slab);
    else
      corr_level<true, false, PB0, 64, 16, 6, 5, 11, 2, 6, 8, 1, 1, 0>(
          bid - 480, wv, lane, g0, s0, m0, ws, gl, r_lds, slab);
  } else {
    const int pb = bid - 496;
    const int pair = pb >> 4;   // 0..31
    const int k = pb & 15;      // slice 0..15
    const int lev = pair >> 3;
    const int b = pair & 7;
    float* part = ws + WS_PART + (pair * 16 + k) * 2;
    if (lev == 0)      prep_partial_level<64, 16, 6, 5>(g0, s0, m0, b, k, part, sw);
    else if (lev == 1) prep_partial_level<32, 32, 13, 10>(g1, s1, m1, b, k, part, sw);
    else if (lev == 2) prep_partial_level<16, 64, 26, 19>(g2, s2, m2, b, k, part, sw);
    else               prep_partial_level<8, 128, 53, 38>(g3, s3, m3, b, k, part, sw);
  }
}

// ---------------- loss2 (partial path): sc + partial sums inline ------------
__global__ __launch_bounds__(256) void loss2_kernel(const float* __restrict__ u,
                                                    const float* __restrict__ v,
                                                    const float* __restrict__ hd,
                                                    float* __restrict__ ws) {
  __shared__ float sw[4];
  const int e = blockIdx.x * 256 + threadIdx.x;
  float term = 0.0f;
  if (e < N_ENTRIES) {
    int lev, start, OH, np, base, E;
    float mpp;
    if (e < 968)        { lev = 0; start = 0;     OH = 11; mpp = 6.4f; np = 2;  base = PB0; E = 968; }
    else if (e < 4168)  { lev = 1; start = 968;   OH = 20; mpp = 3.2f; np = 4;  base = PB1; E = 3200; }
    else if (e < 16336) { lev = 2; start = 4168;  OH = 39; mpp = 1.6f; np = 8;  base = PB2; E = 12168; }
    else                { lev = 3; start = 16336; OH = 76; mpp = 0.8f; np = 16; base = PB3; E = 46208; }
    const int r = e - start;
    const int ow2 = OH * OH;
    const int b = r / ow2;
    // sc inline (identical op order to the old prep_final_kernel)
    const float* p = ws + WS_PART + (lev * 8 + b) * 32;
    float s1 = 0.0f, s2 = 0.0f;
    for (int kk = 0; kk < 16; ++kk) {
      s1 += p[2 * kk];
      s2 += p[2 * kk + 1];
    }
    const float norm = sqrtf(s1);
    const float denom = fmaxf(sqrtf(s2 + 1e-8f), 1e-6f);
    const float scv = 2.0f / (fmaxf(norm, 1e-12f) * denom);
    // gt position, replicating the reference fp32 op order
    float t = hd[b] * 10.0f;
    t = t / 180.0f;
    t = t * 3.14159265358979323846f;
    const float cs = cosf(t), sn = sinf(t);
    const float gdx = -u[b] * 20.0f;
    const float gdy = -v[b] * 20.0f;
    const float dxr = -gdx * cs + gdy * sn;
    const float dyr = gdx * sn + gdy * cs;
    int wi = (int)rintf(OH * 0.5f - 0.5f + dxr / mpp);  // rintf = round-half-even
    int hi = (int)rintf(OH * 0.5f - 0.5f + dyr / mpp);
    wi = min(max(wi, 0), OH - 1);
    hi = min(max(hi, 0), OH - 1);
    const int posoff = (b * OH + hi) * OH + wi;
    // raw/rp: same summation order as the old reduce_kernel
    float raw = 0.0f, rp = 0.0f;
    for (int pp = 0; pp < np; ++pp) {
      raw += ws[base + pp * E + r];
      rp += ws[base + pp * E + posoff];
    }
    const float z = 10.0f * scv * (raw - rp);
    const float spl = fmaxf(z, 0.0f) + log1pf(expf(-fabsf(z)));
    term = spl / (8.0f * (float)(ow2 - 1));
  }
  const float tot = block_sum256(term, sw);
  if (threadIdx.x == 0) ws[WS_CORR + blockIdx.x] = tot;
}

// ---------------- final: deterministic 245-way sum -> out -------------------
__global__ __launch_bounds__(256) void final_kernel(const float* __restrict__ ws,
                                                    float* __restrict__ out) {
  __shared__ float sw[4];
  const int t = threadIdx.x;
  float v = (t < 245) ? ws[WS_CORR + t] : 0.0f;
  const float tot = block_sum256(v, sw);
  if (t == 0) out[0] = tot;
}

// ---------------- standalone corr (FALLBACK, atomic accumulate) -------------
__global__ __launch_bounds__(256, 1) void corr_kernel_fb(
    const float* g0, const float* s0, const float* m0, const float* g1,
    const float* s1, const float* m1, const float* g2, const float* s2,
    const float* m2, const float* g3, const float* s3, const float* m3,
    float* ws) {
  __shared__ float smem[5888];
  const int wv = threadIdx.x >> 6;
  const int lane = threadIdx.x & 63;
  float* slab = smem + wv * 1056;
  float* gl = smem + 4224 + wv * 416;
  float* r_lds = smem;
  const int bid = blockIdx.x;
  if (bid < 384)
    corr_level<false, true, PB3, 8, 128, 53, 38, 76, 10, 190, 8, 8, 3, 16336>(
        bid, wv, lane, g3, s3, m3, ws, gl, r_lds, slab);
  else if (bid < 448)
    corr_level<false, false, PB2, 16, 64, 26, 19, 39, 5, 50, 8, 4, 1, 4168>(
        bid - 384, wv, lane, g2, s2, m2, ws, gl, r_lds, slab);
  else if (bid < 480)
    corr_level<false, false, PB1, 32, 32, 13, 10, 20, 3, 15, 16, 1, 1, 968>(
        bid - 448, wv, lane, g1, s1, m1, ws, gl, r_lds, slab);
  else
    corr_level<false, false, PB0, 64, 16, 6, 5, 11, 2, 6, 8, 1, 1, 0>(
        bid - 480, wv, lane, g0, s0, m0, ws, gl, r_lds, slab);
}

// ---------------- loss (FALLBACK: reads reduced WS_CORR, atomic out) --------
__global__ __launch_bounds__(256) void loss_kernel(const float* __restrict__ u,
                                                   const float* __restrict__ v,
                                                   const float* __restrict__ hd,
                                                   const float* __restrict__ ws,
                                                   float* __restrict__ out) {
  __shared__ float sw[4];
  const int e = blockIdx.x * 256 + threadIdx.x;
  float term = 0.0f;
  if (e < N_ENTRIES) {
    int lev, start, OH;
    float mpp;
    if (e < 968)        { lev = 0; start = 0;     OH = 11; mpp = 6.4f; }
    else if (e < 4168)  { lev = 1; start = 968;   OH = 20; mpp = 3.2f; }
    else if (e < 16336) { lev = 2; start = 4168;  OH = 39; mpp = 1.6f; }
    else                { lev = 3; start = 16336; OH = 76; mpp = 0.8f; }
    const int r = e - start;
    const int ow2 = OH * OH;
    const int b = r / ow2;
    const float scv = ws[WS_SC + lev * 8 + b];
    float t = hd[b] * 10.0f;
    t = t / 180.0f;
    t = t * 3.14159265358979323846f;
    const float cs = cosf(t), sn = sinf(t);
    const float gdx = -u[b] * 20.0f;
    const float gdy = -v[b] * 20.0f;
    const float dxr = -gdx * cs + gdy * sn;
    const float dyr = gdx * sn + gdy * cs;
    int wi = (int)rintf(OH * 0.5f - 0.5f + dxr / mpp);
    int hi = (int)rintf(OH * 0.5f - 0.5f + dyr / mpp);
    wi = min(max(wi, 0), OH - 1);
    hi = min(max(hi, 0), OH - 1);
    const float raw = ws[WS_CORR + e];
    const float rp = ws[WS_CORR + start + (b * OH + hi) * OH + wi];
    const float z = 10.0f * scv * (raw - rp);
    const float spl = fmaxf(z, 0.0f) + log1pf(expf(-fabsf(z)));
    term = spl / (8.0f * (float)(ow2 - 1));
  }
  const float tot = block_sum256(term, sw);
  if (threadIdx.x == 0) atomicAdd(out, tot);
}

// ---------------------------------------------------------------------------
extern "C" void kernel_launch(void* const* d_in, const int* in_sizes, int n_in,
                              void* d_out, int out_size, void* d_ws,
                              size_t ws_size, hipStream_t stream) {
  const float* g0 = (const float*)d_in[0];
  const float* s0 = (const float*)d_in[1];
  const float* m0 = (const float*)d_in[2];
  const float* g1 = (const float*)d_in[3];
  const float* s1 = (const float*)d_in[4];
  const float* m1 = (const float*)d_in[5];
  const float* g2 = (const float*)d_in[6];
  const float* s2 = (const float*)d_in[7];
  const float* m2 = (const float*)d_in[8];
  const float* g3 = (const float*)d_in[9];
  const float* s3 = (const float*)d_in[10];
  const float* m3 = (const float*)d_in[11];
  const float* u  = (const float*)d_in[12];
  const float* v  = (const float*)d_in[13];
  const float* hd = (const float*)d_in[14];
  float* ws = (float*)d_ws;
  float* out = (float*)d_out;
  const bool use_partial = (ws_size >= (size_t)WS_NEED_BYTES);

  if (use_partial) {
    // 3 launches: fused(corr+prep) -> loss2 -> final. No fp atomics.
    fused_kernel<<<dim3(1008), dim3(256), 0, stream>>>(
        g0, s0, m0, g1, s1, m1, g2, s2, m2, g3, s3, m3, ws);
    loss2_kernel<<<dim3(245), dim3(256), 0, stream>>>(u, v, hd, ws);
    final_kernel<<<dim3(1), dim3(256), 0, stream>>>(ws, out);
  } else {
    init_kernel<<<dim3(245), dim3(256), 0, stream>>>(ws, out);
    prep_partial_kernel<<<dim3(512), dim3(256), 0, stream>>>(
        g0, s0, m0, g1, s1, m1, g2, s2, m2, g3, s3, m3, ws);
    prep_final_kernel<<<dim3(1), dim3(64), 0, stream>>>(ws);
    corr_kernel_fb<<<dim3(496), dim3(256), 0, stream>>>(
        g0, s0, m0, g1, s1, m1, g2, s2, m2, g3, s3, m3, ws);
    loss_kernel<<<dim3(245), dim3(256), 0, stream>>>(u, v, hd, ws, out);
  }
}